// Round 3
// baseline (760.344 us; speedup 1.0000x reference)
//
#include <hip/hip_runtime.h>

// FactorizedSpectralConv: B=8, S1=S2=256, C=64, M1=M2=32.
// Fused per-dim kernels: truncated DFT (MFMA f16) -> complex mix (VALU fp32)
// -> iDFT (MFMA f16). B-operands staged in LDS in fragment order; no inline asm.
//
// MFMA mapping discipline: logical k index f(g2,e) = 8*g2 + e is used for BOTH
// A (tables built by init kernel) and B (staging layout). With A/B HW layouts
// being mirror transposes (standard CDNA), any consistent bijection is correct.
// C/D layout used: col = lane&31, row = (reg&3) + 8*(reg>>2) + 4*(lane>>5)  [verified].

namespace {

constexpr int S = 256, C = 64;

typedef _Float16 f16;
typedef _Float16 f16x2 __attribute__((ext_vector_type(2)));
typedef _Float16 f16x4 __attribute__((ext_vector_type(4)));
typedef _Float16 f16x8 __attribute__((ext_vector_type(8)));
typedef float f32x16 __attribute__((ext_vector_type(16)));

// ws layout (float offsets)
constexpr int OFF_KT0  = 0;        // kT0[r][j][i][{R,I}] fp32 : 32*64*64*2 = 262144
constexpr int OFF_KT1  = 262144;   // kT1 same
constexpr int OFF_FWDF = 524288;   // fwd A-frag table: 16384 f16 (8192 floats)
constexpr int OFF_INVF = 532480;   // inv A-frag table: 16384 f16 (8192 floats)
// total 540672 floats = 2.06 MB

// LDS geometry: rows of 256 col-slots, 16B per col, +16B pad per 8 cols.
constexpr int P   = 4624;          // row pitch bytes (4592 used, 16B-aligned, bank-skewed)
constexpr int XFO = 8 * P;         // Xf region (8 rows) after the 8 Bf/Yf rows
constexpr int LDS_BYTES = 16 * P;  // 73984 B

__device__ __host__ inline int cadr(int c) { return c * 16 + (c >> 3) * 16; }

// ---- init: A-fragment tables (f16, fragment order, k = kk*16 + 8*g2 + e) ----
__global__ void k_init_frag(float* __restrict__ ws) {
  int t = blockIdx.x * 256 + threadIdx.x;  // 0..32767
  f16* fwdF = (f16*)(ws + OFF_FWDF);
  f16* invF = (f16*)(ws + OFF_INVF);
  if (t < 16384) {
    // fwdF[((kk*2+mt)*64 + lane)*8 + e] = trig(mc = mt*32+(lane&31), x = kk*16+8*(lane>>5)+e)
    int e = t & 7, lane = (t >> 3) & 63, mtkk = t >> 9;
    int mt = mtkk & 1, kk = mtkk >> 1;
    int mc = mt * 32 + (lane & 31);
    int x = kk * 16 + 8 * (lane >> 5) + e;
    int r = mc >> 1;
    double ang = (double)((r * x) & 255) * (3.14159265358979323846 / 128.0);
    double v = (mc & 1) ? -sin(ang) : cos(ang);
    fwdF[t] = (f16)(float)v;
  } else {
    // invF[((kk*8+mtg)*64 + lane)*8 + e] = w_r*trig(r, u = mtg*32+(lane&31))/256,
    //   mcv = kk*16+8*(lane>>5)+e, r = mcv>>1; even mcv: cos, odd: -sin
    int t2 = t - 16384;
    int e = t2 & 7, lane = (t2 >> 3) & 63, mtg = (t2 >> 9) & 7, kk = t2 >> 12;
    int u = mtg * 32 + (lane & 31);
    int mcv = kk * 16 + 8 * (lane >> 5) + e;
    int r = mcv >> 1;
    double wgt = (r == 0) ? 1.0 : 2.0;
    double ang = (double)((r * u) & 255) * (3.14159265358979323846 / 128.0);
    double v = (mcv & 1) ? -wgt * sin(ang) : wgt * cos(ang);
    invF[t2] = (f16)(float)(v * (1.0 / 256.0));
  }
}

// kT[((r*64+j)*64+i)*2 + {0,1}] = {kr[r][i][j], ki[r][i][j]}  (raw)
__global__ void k_init_kT(const float* __restrict__ kr, const float* __restrict__ ki,
                          float* __restrict__ kTd) {
  int t = blockIdx.x * 256 + threadIdx.x;  // t = (r*64+j)*64+i
  int r = t >> 12, j = (t >> 6) & 63, i = t & 63;
  int src = (r * 64 + i) * 64 + j;
  kTd[2 * t + 0] = kr[src];
  kTd[2 * t + 1] = ki[src];
}

// ---- main fused kernel ----
// Block = (b, 4 slabs along the non-transformed axis), 512 threads (8 waves).
// LDS: Bf double-buffer (2 x 4 rows, reused as Yf 8 rows) + Xf (8 rows).
template <int DIM>
__launch_bounds__(512, 4)
__global__ void k_dim(const float* __restrict__ X, const float* __restrict__ ws,
                      float* __restrict__ out) {
  __shared__ char sm[LDS_BYTES] __attribute__((aligned(16)));

  const int tid = threadIdx.x;
  const int l = tid & 63, w = tid >> 6;
  const int g2 = l >> 5, l31 = l & 31;
  const int n0 = w * 32;                   // wave's 32-col window
  const int b = blockIdx.x >> 6;
  const int t4 = (blockIdx.x & 63) * 4;    // first slab
  const size_t bbase = (size_t)b * (S * S * C);
  const f16* fwdF = (const f16*)(ws + OFF_FWDF);
  const f16* invF = (const f16*)(ws + OFF_INVF);
  const float* kT = ws + (DIM == 0 ? OFF_KT0 : OFF_KT1);

  auto gofs = [&](int u, int c) -> size_t {
    if (DIM == 0)
      return bbase + (size_t)u * (S * C) + (size_t)(t4 + (c >> 6)) * C + (c & 63);
    else
      return bbase + (size_t)(t4 + (c >> 6)) * (S * C) + (size_t)u * C + (c & 63);
  };

  // staging assignment: wave -> (ug = w>>1 of 4 u-subrows, half = w&1 of col range)
  const int ug = w >> 1;
  const int c1 = (w & 1) * 128 + l;
  const int c2 = c1 + 64;

  float r1[8], r2[8];
  auto stage_load = [&](int u0) {
#pragma unroll
    for (int j = 0; j < 8; ++j) r1[j] = X[gofs(u0 + ug * 8 + j, c1)];
#pragma unroll
    for (int j = 0; j < 8; ++j) r2[j] = X[gofs(u0 + ug * 8 + j, c2)];
  };
  auto stage_write = [&](int buf) {
    f16x8 v1, v2;
#pragma unroll
    for (int j = 0; j < 8; ++j) { v1[j] = (f16)r1[j]; v2[j] = (f16)r2[j]; }
    char* base = sm + buf * (4 * P) + ug * P;
    *(f16x8*)(base + cadr(c1)) = v1;
    *(f16x8*)(base + cadr(c2)) = v2;
  };

  // ---------------- Phase 1: truncated DFT via MFMA ----------------
  f32x16 acc0, acc1;
#pragma unroll
  for (int q = 0; q < 16; ++q) { acc0[q] = 0.f; acc1[q] = 0.f; }

  stage_load(0);
  stage_write(0);
  __syncthreads();

  for (int ch = 0; ch < 8; ++ch) {
    if (ch < 7) stage_load((ch + 1) * 32);
    const char* bbuf = sm + (ch & 1) * (4 * P);
#pragma unroll
    for (int ks = 0; ks < 2; ++ks) {
      const int kk = ch * 2 + ks;
      f16x8 bf = *(const f16x8*)(bbuf + (ks * 2 + g2) * P + cadr(n0 + l31));
      f16x8 a0 = *(const f16x8*)(fwdF + ((size_t)(kk * 2 + 0) * 64 + l) * 8);
      f16x8 a1 = *(const f16x8*)(fwdF + ((size_t)(kk * 2 + 1) * 64 + l) * 8);
      acc0 = __builtin_amdgcn_mfma_f32_32x32x16_f16(a0, bf, acc0, 0, 0, 0);
      acc1 = __builtin_amdgcn_mfma_f32_32x32x16_f16(a1, bf, acc1, 0, 0, 0);
    }
    if (ch < 7) {
      stage_write((ch + 1) & 1);
      __syncthreads();
    }
  }

  // ---------------- Phase 2: acc -> Xf (f16, fragment-order rows) ----------------
  // C-layout: col = n0 + l31, mc = (reg&3) + 8*(reg>>2) + 4*g2 (+32 for acc1)
  {
    char* xf = sm + XFO;
    const int co = cadr(n0 + l31) + 8 * g2;   // e-base = 4*g2 -> byte 8*g2
#pragma unroll
    for (int q = 0; q < 4; ++q) {
      f16x4 v0, v1;
#pragma unroll
      for (int t = 0; t < 4; ++t) { v0[t] = (f16)acc0[4 * q + t]; v1[t] = (f16)acc1[4 * q + t]; }
      *(f16x4*)(xf + q * P + co) = v0;        // rows mc>>3 = q
      *(f16x4*)(xf + (q + 4) * P + co) = v1;  // rows q+4
    }
  }
  __syncthreads();

  // ---------------- Phase 3: complex channel mix (fp32 VALU) ----------------
  // thread: mode r = tid>>4, out-channels i0..i0+3; reads Xf, writes Yf (Bf region).
  {
    const int r  = tid >> 4;
    const int i0 = (tid & 15) * 4;
    const char* xf = sm + XFO + (r >> 2) * P;  // row (2r)>>3 = r>>2
    char* yf = sm + (r >> 2) * P;
    const int eo = (r & 3) * 4;                // byte offset of (xr,xi) pair

    float yR[4][4], yI[4][4];
#pragma unroll
    for (int p = 0; p < 4; ++p)
#pragma unroll
      for (int i = 0; i < 4; ++i) { yR[p][i] = 0.f; yI[p][i] = 0.f; }

    const float4* kp = (const float4*)kT + (size_t)r * 2048 + (i0 >> 1);
#pragma unroll 2
    for (int j = 0; j < 64; ++j) {
      float4 ka = kp[j * 32 + 0];   // {kR,kI} for i0, i0+1
      float4 kb = kp[j * 32 + 1];   // i0+2, i0+3
#pragma unroll
      for (int p = 0; p < 4; ++p) {
        f16x2 x2 = *(const f16x2*)(xf + cadr(p * 64 + j) + eo);
        float xr = (float)x2[0], xi = (float)x2[1];
        yR[p][0] += ka.x * xr - ka.y * xi;  yI[p][0] += ka.x * xi + ka.y * xr;
        yR[p][1] += ka.z * xr - ka.w * xi;  yI[p][1] += ka.z * xi + ka.w * xr;
        yR[p][2] += kb.x * xr - kb.y * xi;  yI[p][2] += kb.x * xi + kb.y * xr;
        yR[p][3] += kb.z * xr - kb.w * xi;  yI[p][3] += kb.z * xi + kb.w * xr;
      }
    }
#pragma unroll
    for (int p = 0; p < 4; ++p)
#pragma unroll
      for (int i = 0; i < 4; ++i) {
        f16x2 v = {(f16)yR[p][i], (f16)yI[p][i]};
        *(f16x2*)(yf + cadr(p * 64 + i0 + i) + eo) = v;
      }
  }
  __syncthreads();

  // ---------------- Phase 4: iDFT via MFMA -> global ----------------
  const int colg = n0 + l31;
  const int pp = colg >> 6, jj = colg & 63;
#pragma unroll 1
  for (int h = 0; h < 2; ++h) {
    f32x16 a4[4];
#pragma unroll
    for (int mt = 0; mt < 4; ++mt)
#pragma unroll
      for (int q = 0; q < 16; ++q) a4[mt][q] = 0.f;

#pragma unroll
    for (int kk = 0; kk < 4; ++kk) {
      f16x8 bf = *(const f16x8*)(sm + (kk * 2 + g2) * P + cadr(colg));
      const f16* ab = invF + ((size_t)(kk * 8 + h * 4) * 64 + l) * 8;
      f16x8 A0 = *(const f16x8*)(ab + 0 * 512);
      f16x8 A1 = *(const f16x8*)(ab + 1 * 512);
      f16x8 A2 = *(const f16x8*)(ab + 2 * 512);
      f16x8 A3 = *(const f16x8*)(ab + 3 * 512);
      a4[0] = __builtin_amdgcn_mfma_f32_32x32x16_f16(A0, bf, a4[0], 0, 0, 0);
      a4[1] = __builtin_amdgcn_mfma_f32_32x32x16_f16(A1, bf, a4[1], 0, 0, 0);
      a4[2] = __builtin_amdgcn_mfma_f32_32x32x16_f16(A2, bf, a4[2], 0, 0, 0);
      a4[3] = __builtin_amdgcn_mfma_f32_32x32x16_f16(A3, bf, a4[3], 0, 0, 0);
    }
#pragma unroll
    for (int mt = 0; mt < 4; ++mt) {
#pragma unroll
      for (int reg = 0; reg < 16; ++reg) {
        int u = (h * 4 + mt) * 32 + (reg & 3) + 8 * (reg >> 2) + 4 * g2;
        size_t g = (DIM == 0)
                       ? bbase + (size_t)u * (S * C) + (size_t)(t4 + pp) * C + jj
                       : bbase + (size_t)(t4 + pp) * (S * C) + (size_t)u * C + jj;
        if (DIM == 0) out[g] = a4[mt][reg];
        else          out[g] += a4[mt][reg];
      }
    }
  }
}

}  // namespace

extern "C" void kernel_launch(void* const* d_in, const int* in_sizes, int n_in,
                              void* d_out, int out_size, void* d_ws, size_t ws_size,
                              hipStream_t stream) {
  (void)in_sizes; (void)n_in; (void)out_size; (void)ws_size;
  const float* X   = (const float*)d_in[0];
  const float* k0r = (const float*)d_in[1];
  const float* k0i = (const float*)d_in[2];
  const float* k1r = (const float*)d_in[3];
  const float* k1i = (const float*)d_in[4];
  float* out = (float*)d_out;
  float* ws  = (float*)d_ws;

  k_init_frag<<<128, 256, 0, stream>>>(ws);
  k_init_kT<<<512, 256, 0, stream>>>(k0r, k0i, ws + OFF_KT0);
  k_init_kT<<<512, 256, 0, stream>>>(k1r, k1i, ws + OFF_KT1);
  k_dim<0><<<512, 512, 0, stream>>>(X, ws, out);   // writes out
  k_dim<1><<<512, 512, 0, stream>>>(X, ws, out);   // accumulates into out
}